// Round 2
// baseline (216.011 us; speedup 1.0000x reference)
//
#include <hip/hip_runtime.h>
#include <math.h>

// Chamfer k-NN (k=16, L2), R15: R14 (1-D binned window scan) with the
// stop-radius units bug fixed.
// R14 post-mortem: s[] holds c-space values (c = d2 - |q|^2); the drain
// computed rtau_pw = sqrt(t15)+w on the C-SPACE value -> radius too small
// (and NaN when t15<0) -> scan stopped before reaching true neighbors ->
// absmax 0.25. Fix: rtau_pw = sqrt(max(t15 + q2, 0)) + w (true d2-space).
// Structure recap:
//   init    : zero out[0], min/max sentinels.
//   pack    : pred4=(src+flow,|.|^2), tgt4=(tgt,|.|^2) + global x-min/max.
//   binsort : counting-sort the 4 point sets into NB=512 x-bins.
//   scan    : two-sided outward scan per query, 8 lanes/query stride-8,
//             per-lane top-16 via LDS queue + batched bitonic drains,
//             octet-shared tau (min of s[15] over 8 lanes = upper bound on
//             the union's 16th). Stop: signed dx >= sqrt(tau_d2) + w.
//             Epilogue merges 8 lane-lists via shfl_xor halvers and
//             atomically accumulates mean(sqrt(d2)).

#define INFV    3.0e38f
#define QDEPTH  32
#define NB      512

__device__ __forceinline__ void ce(float& a, float& b) {
    float lo = fminf(a, b);
    b = fmaxf(a, b);
    a = lo;
}

// bitonic merge-sort of a bitonic 16-seq (stages 8,4,2,1 = 32 CE), ascending
__device__ __forceinline__ void bitonic16(float (&s)[16]) {
    ce(s[0],s[8]);  ce(s[1],s[9]);  ce(s[2],s[10]); ce(s[3],s[11]);
    ce(s[4],s[12]); ce(s[5],s[13]); ce(s[6],s[14]); ce(s[7],s[15]);
    ce(s[0],s[4]);  ce(s[1],s[5]);  ce(s[2],s[6]);  ce(s[3],s[7]);
    ce(s[8],s[12]); ce(s[9],s[13]); ce(s[10],s[14]);ce(s[11],s[15]);
    ce(s[0],s[2]);  ce(s[1],s[3]);  ce(s[4],s[6]);  ce(s[5],s[7]);
    ce(s[8],s[10]); ce(s[9],s[11]); ce(s[12],s[14]);ce(s[13],s[15]);
    ce(s[0],s[1]);  ce(s[2],s[3]);  ce(s[4],s[5]);  ce(s[6],s[7]);
    ce(s[8],s[9]);  ce(s[10],s[11]);ce(s[12],s[13]);ce(s[14],s[15]);
}

// Merge up to 8 queued values (qb[(base+i)*256], i<cnt-base) into sorted s[16].
__device__ __forceinline__ void drain_batch(float (&s)[16], const float* qb,
                                            int base, int cnt)
{
    float q[8];
#pragma unroll
    for (int i = 0; i < 8; ++i) {
        float v = qb[(base + i) * 256];
        q[i] = (base + i < cnt) ? v : INFV;
    }
    // sort8 ascending -- Batcher odd-even, 19 CE
    ce(q[0],q[1]); ce(q[2],q[3]); ce(q[4],q[5]); ce(q[6],q[7]);
    ce(q[0],q[2]); ce(q[1],q[3]); ce(q[4],q[6]); ce(q[5],q[7]);
    ce(q[1],q[2]); ce(q[5],q[6]);
    ce(q[0],q[4]); ce(q[1],q[5]); ce(q[2],q[6]); ce(q[3],q[7]);
    ce(q[2],q[4]); ce(q[3],q[5]);
    ce(q[1],q[2]); ce(q[3],q[4]); ce(q[5],q[6]);
    // bitonic halver vs sorted s[16]
#pragma unroll
    for (int i = 0; i < 8; ++i) s[8 + i] = fminf(s[8 + i], q[7 - i]);
    bitonic16(s);
}

// order-preserving float<->uint map for atomicMin/Max
__device__ __forceinline__ unsigned fmap(float f) {
    unsigned u = __float_as_uint(f);
    return (u & 0x80000000u) ? ~u : (u | 0x80000000u);
}
__device__ __forceinline__ float funmap(unsigned u) {
    unsigned v = (u & 0x80000000u) ? (u & 0x7fffffffu) : ~u;
    return __uint_as_float(v);
}

__global__ void init_kernel(float* __restrict__ out, unsigned* __restrict__ mm) {
    if (threadIdx.x == 0) {
        out[0] = 0.0f;          // replaces memset (poisoned 0xAA)
        mm[0] = 0xFFFFFFFFu;    // min sentinel (mapped order)
        mm[1] = 0u;             // max sentinel
    }
}

__global__ __launch_bounds__(256) void pack_kernel(
    const float* __restrict__ src, const float* __restrict__ tgt,
    const float* __restrict__ flow,
    float4* __restrict__ pred4, float4* __restrict__ tgt4,
    unsigned* __restrict__ mm, int BN, int BM)
{
    int i = blockIdx.x * 256 + threadIdx.x;
    float lmin = INFV, lmax = -INFV;
    if (i < BN) {
        float x = src[3 * i + 0] + flow[3 * i + 0];
        float y = src[3 * i + 1] + flow[3 * i + 1];
        float z = src[3 * i + 2] + flow[3 * i + 2];
        pred4[i] = make_float4(x, y, z, fmaf(x, x, fmaf(y, y, z * z)));
        lmin = fminf(lmin, x); lmax = fmaxf(lmax, x);
    }
    if (i < BM) {
        float x = tgt[3 * i + 0];
        float y = tgt[3 * i + 1];
        float z = tgt[3 * i + 2];
        tgt4[i] = make_float4(x, y, z, fmaf(x, x, fmaf(y, y, z * z)));
        lmin = fminf(lmin, x); lmax = fmaxf(lmax, x);
    }
#pragma unroll
    for (int off = 32; off > 0; off >>= 1) {
        lmin = fminf(lmin, __shfl_down(lmin, off));
        lmax = fmaxf(lmax, __shfl_down(lmax, off));
    }
    if ((threadIdx.x & 63) == 0) {
        atomicMin(mm + 0, fmap(lmin));
        atomicMax(mm + 1, fmap(lmax));
    }
}

__device__ __forceinline__ int binof(float x, float xmin, float sc) {
    int bn = (int)((x - xmin) * sc);
    return bn < 0 ? 0 : (bn > NB - 1 ? NB - 1 : bn);
}

// counting-sort one point set into x-bins. blockIdx.x: 0=pred b0, 1=pred b1,
// 2=tgt b0, 3=tgt b1. Order within a bin is arbitrary (scan only needs the
// within-bin x-spread <= w bound, which true-range bins guarantee).
__global__ __launch_bounds__(1024) void binsort_kernel(
    const float4* __restrict__ pred4, const float4* __restrict__ tgt4,
    float4* __restrict__ ps4, float4* __restrict__ ts4,
    int* __restrict__ goffs, const unsigned* __restrict__ mm, int N, int M)
{
    const int a = blockIdx.x, tid = threadIdx.x;
    const int n = (a < 2) ? N : M;
    const float4* src = (a < 2) ? pred4 + (size_t)a * N : tgt4 + (size_t)(a - 2) * M;
    float4* dst       = (a < 2) ? ps4   + (size_t)a * N : ts4  + (size_t)(a - 2) * M;

    __shared__ int hist[NB];
    __shared__ int offs[NB + 1];
    __shared__ int cur[NB];
    const float xmin = funmap(mm[0]);
    const float xmax = funmap(mm[1]);
    const float range = xmax - xmin;
    const float sc = (range > 0.f) ? (float)NB / range : 0.f;

    if (tid < NB) { hist[tid] = 0; cur[tid] = 0; }
    __syncthreads();
    for (int i = tid; i < n; i += 1024)
        atomicAdd(&hist[binof(src[i].x, xmin, sc)], 1);
    __syncthreads();
    // inclusive Hillis-Steele scan over NB entries
    for (int off = 1; off < NB; off <<= 1) {
        int t = 0;
        if (tid < NB && tid >= off) t = hist[tid - off];
        __syncthreads();
        if (tid < NB) hist[tid] += t;
        __syncthreads();
    }
    if (tid < NB) offs[tid + 1] = hist[tid];
    if (tid == 0) offs[0] = 0;
    __syncthreads();
    for (int i = tid; i < n; i += 1024) {
        float4 v = src[i];
        int bn = binof(v.x, xmin, sc);
        int slot = atomicAdd(&cur[bn], 1);
        dst[offs[bn] + slot] = v;
    }
    if (tid <= NB) goffs[a * (NB + 1) + tid] = offs[tid];
}

__global__ __launch_bounds__(256, 4) void scan_kernel(
    const float4* __restrict__ ps4, const float4* __restrict__ ts4,
    const int* __restrict__ goffs, const unsigned* __restrict__ mm,
    float* __restrict__ out, int N, int M, float scale_out)
{
    __shared__ float qbuf[QDEPTH * 256];   // 32 KB per-thread queues, stride 256
    __shared__ float wsum[4];

    const int tid = threadIdx.x;
    const int z = blockIdx.y, b = z >> 1, dir = z & 1;
    const int nq   = dir ? M : N;
    const int nref = dir ? N : M;
    const float4* Q = dir ? (ts4 + (size_t)b * M) : (ps4 + (size_t)b * N);
    const float4* R = dir ? (ps4 + (size_t)b * N) : (ts4 + (size_t)b * M);
    const int oid   = dir ? b : 2 + b;     // offsets id of the REF array

    // wave-chunk remap: mix dense/sparse x-regions across each SIMD's waves
    const int W = gridDim.x * 4;
    const int wv = blockIdx.x * 4 + (tid >> 6);
    const int c = ((W & (W - 1)) == 0) ? ((wv * 45) & (W - 1)) : wv;
    const int qidx = c * 8 + ((tid >> 3) & 7);
    const bool qv = qidx < nq;

    float4 q = qv ? Q[qidx] : make_float4(0.f, 0.f, 0.f, 0.f);
    const float qx = q.x, q2 = q.w;
    const float nx = -2.f * q.x, ny = -2.f * q.y, nz = -2.f * q.z;

    const float xmin = funmap(mm[0]);
    const float range = funmap(mm[1]) - xmin;
    const float w = range * (1.0f / NB);
    const float sc = (range > 0.f) ? (float)NB / range : 0.f;
    const int start = goffs[oid * (NB + 1) + binof(qx, xmin, sc)];

    float s[16];
#pragma unroll
    for (int i = 0; i < 16; ++i) s[i] = INFV;
    float tau     = qv ? INFV : -INFV;     // invalid octets never enqueue
    float rtau_pw = qv ? INFV : -INFV;     // and stop after one group
    int   cnt = 0, lim = 17;               // first drain as soon as a lane
                                           // can have a real s[15]
    const int l = tid & 7;
    const float* qb_tid = qbuf + tid;

    // NOTE: s[] is c-space (c = d2 - q2). tau (c-space) is valid for the
    // enqueue compare (octet shares one query -> same q2 offset); the STOP
    // radius must convert to true d2: sqrt(max(t15 + q2, 0)) + w.
#define DRAIN_ALL() do {                                            \
        drain_batch(s, qb_tid, 0, cnt);                             \
        if (__ballot(cnt >  8)) drain_batch(s, qb_tid,  8, cnt);    \
        if (__ballot(cnt > 16)) drain_batch(s, qb_tid, 16, cnt);    \
        if (__ballot(cnt > 24)) drain_batch(s, qb_tid, 24, cnt);    \
        cnt = 0;                                                    \
        float t15 = s[15];                                          \
        t15 = fminf(t15, __shfl_xor(t15, 1));                       \
        t15 = fminf(t15, __shfl_xor(t15, 2));                       \
        t15 = fminf(t15, __shfl_xor(t15, 4));                       \
        if (qv) { tau = t15;                                        \
                  rtau_pw = sqrtf(fmaxf(t15 + q2, 0.0f)) + w; }     \
    } while (0)

    // 8 candidates per lane per group; loads hoisted ahead of the act-chain.
    // Unconditional slot write + predicated count advance (proven pattern).
#define PROC8(DIRSGN) do {                                          \
        float4 rr[8];                                               \
        const int pLast = p + (DIRSGN) * 56;                        \
        if (((unsigned)p < (unsigned)nref) &&                       \
            ((unsigned)pLast < (unsigned)nref)) {                   \
            _Pragma("unroll")                                       \
            for (int u = 0; u < 8; ++u)                             \
                rr[u] = R[p + (DIRSGN) * (u * 8)];                  \
        } else {                                                    \
            _Pragma("unroll")                                       \
            for (int u = 0; u < 8; ++u) {                           \
                int pi = p + (DIRSGN) * (u * 8);                    \
                rr[u] = R[((unsigned)pi < (unsigned)nref) ? pi : 0];\
            }                                                       \
        }                                                           \
        _Pragma("unroll")                                           \
        for (int u = 0; u < 8; ++u) {                               \
            const int pi = p + (DIRSGN) * (u * 8);                  \
            const bool inb = (unsigned)pi < (unsigned)nref;         \
            const float dxs = ((DIRSGN) > 0) ? (rr[u].x - qx)       \
                                             : (qx - rr[u].x);      \
            const bool go = act & inb & (dxs < rtau_pw);            \
            const float c = fmaf(nx, rr[u].x, fmaf(ny, rr[u].y,     \
                            fmaf(nz, rr[u].z, rr[u].w)));           \
            qbuf[cnt * 256 + tid] = c;                              \
            cnt += (go & (c < tau)) ? 1 : 0;                        \
            act = go;                                               \
        }                                                           \
        p += (DIRSGN) * 64;                                         \
    } while (0)

    // right phase: positions start+l, +8 ...
    {
        int p = start + l;
        bool act = true;
        while (__ballot(act)) {
            PROC8(1);
            if (__ballot(cnt >= lim)) { DRAIN_ALL(); lim = QDEPTH - 7; }
        }
    }
    // left phase: positions start-8+l, -8 ... (covers everything < start)
    {
        int p = start - 8 + l;
        bool act = true;
        while (__ballot(act)) {
            PROC8(-1);
            if (__ballot(cnt >= lim)) { DRAIN_ALL(); lim = QDEPTH - 7; }
        }
    }
    if (__ballot(cnt > 0)) DRAIN_ALL();

#undef PROC8
#undef DRAIN_ALL

    // octet merge: 3 rounds of sorted-list halver + bitonic16 via shfl_xor
#pragma unroll
    for (int r = 1; r <= 4; r <<= 1) {
        float t[16];
#pragma unroll
        for (int i = 0; i < 16; ++i) t[i] = __shfl_xor(s[i], r);
#pragma unroll
        for (int i = 0; i < 16; ++i) s[i] = fminf(s[i], t[15 - i]);
        bitonic16(s);
    }

    float acc = 0.0f;
    if (qv) {
#pragma unroll
        for (int i = 0; i < 16; ++i)
            acc += sqrtf(fmaxf(s[i] + q2, 0.0f));   // true d2 = c + |q|^2
    }
#pragma unroll
    for (int off = 32; off > 0; off >>= 1) acc += __shfl_down(acc, off);
    const int lane = tid & 63, wid = tid >> 6;
    if (lane == 0) wsum[wid] = acc;
    __syncthreads();
    if (tid == 0)
        atomicAdd(out, (wsum[0] + wsum[1] + wsum[2] + wsum[3]) * scale_out);
}

extern "C" void kernel_launch(void* const* d_in, const int* in_sizes, int n_in,
                              void* d_out, int out_size, void* d_ws, size_t ws_size,
                              hipStream_t stream) {
    const float* src  = (const float*)d_in[0];   // pc_source [B,N,3]
    const float* tgt  = (const float*)d_in[1];   // pc_target [B,M,3]
    const float* flow = (const float*)d_in[2];   // pred_flow [B,N,3]
    float* out = (float*)d_out;

    const int B = 2;                              // per reference setup
    const int N = in_sizes[0] / (B * 3);
    const int M = in_sizes[1] / (B * 3);
    const int BN = B * N, BM = B * M;

    // workspace: pred4 | tgt4 | ps4 (bin-sorted pred) | ts4 | goffs | minmax
    float4* pred4 = (float4*)d_ws;
    float4* tgt4  = pred4 + BN;
    float4* ps4   = tgt4 + BM;
    float4* ts4   = ps4 + BN;
    int*    goffs = (int*)(ts4 + BM);             // 4*(NB+1) ints
    unsigned* mm  = (unsigned*)(goffs + 4 * (NB + 1));

    init_kernel<<<1, 64, 0, stream>>>(out, mm);

    int maxBP = (BN > BM) ? BN : BM;
    pack_kernel<<<(maxBP + 255) / 256, 256, 0, stream>>>(
        src, tgt, flow, pred4, tgt4, mm, BN, BM);

    binsort_kernel<<<4, 1024, 0, stream>>>(pred4, tgt4, ps4, ts4, goffs, mm, N, M);

    int maxq = (N > M) ? N : M;
    dim3 grid((maxq + 31) / 32, 2 * B);
    float scale_out = 1.0f / (8.0f * 16.0f * (float)B * (float)N);
    scan_kernel<<<grid, 256, 0, stream>>>(ps4, ts4, goffs, mm, out, N, M, scale_out);
}